// Round 1
// baseline (30.490 us; speedup 1.0000x reference)
//
#include <hip/hip_runtime.h>

// Bicubic resize (align_corners=True, PyTorch a=-0.75) from (N=4096, 224, 224)
// to (12, 52), fused with ReLU. Only the 4x4 tap windows are read: ~46 of 224
// rows per plane -> ~170 MB fetched instead of 822 MB.

#define A_COEF (-0.75f)
#define IN_H 224
#define IN_W 224
#define OUT_H 12
#define OUT_W 52

__device__ __forceinline__ float w_near(float s) {
    // |s| <= 1: (a+2)|s|^3 - (a+3)|s|^2 + 1
    return ((A_COEF + 2.0f) * s - (A_COEF + 3.0f)) * s * s + 1.0f;
}
__device__ __forceinline__ float w_far(float s) {
    // 1 < |s| < 2: a|s|^3 - 5a|s|^2 + 8a|s| - 4a
    return A_COEF * (((s - 5.0f) * s + 8.0f) * s - 4.0f);
}

__global__ __launch_bounds__(256) void bicubic_relu_kernel(
        const float* __restrict__ x, float* __restrict__ out, int total) {
    int t = blockIdx.x * 256 + threadIdx.x;
    if (t >= total) return;

    int ow    = t % OUT_W;
    int rest  = t / OUT_W;
    int oh    = rest % OUT_H;
    int plane = rest / OUT_H;

    // ---- H taps (mirror reference: src = i*(n_in-1)/(n_out-1) in f32) ----
    float srch = ((float)(oh * (IN_H - 1))) / (float)(OUT_H - 1);
    int   h0   = (int)floorf(srch);
    float th   = srch - (float)h0;
    float wh0 = w_far(1.0f + th);
    float wh1 = w_near(th);
    float wh2 = w_near(1.0f - th);
    float wh3 = w_far(2.0f - th);
    int hi[4];
    #pragma unroll
    for (int j = 0; j < 4; ++j) {
        int h = h0 - 1 + j;
        hi[j] = min(max(h, 0), IN_H - 1);
    }

    // ---- W taps ----
    float srcw = ((float)(ow * (IN_W - 1))) / (float)(OUT_W - 1);
    int   w0   = (int)floorf(srcw);
    float tw   = srcw - (float)w0;
    float ww0 = w_far(1.0f + tw);
    float ww1 = w_near(tw);
    float ww2 = w_near(1.0f - tw);
    float ww3 = w_far(2.0f - tw);
    int wi[4];
    #pragma unroll
    for (int j = 0; j < 4; ++j) {
        int w = w0 - 1 + j;
        wi[j] = min(max(w, 0), IN_W - 1);
    }

    const float* p = x + (size_t)plane * (size_t)(IN_H * IN_W);
    float acc = 0.0f;
    float whv[4] = { wh0, wh1, wh2, wh3 };
    #pragma unroll
    for (int j = 0; j < 4; ++j) {
        const float* row = p + hi[j] * IN_W;
        float r = ww0 * row[wi[0]];
        r = fmaf(ww1, row[wi[1]], r);
        r = fmaf(ww2, row[wi[2]], r);
        r = fmaf(ww3, row[wi[3]], r);
        acc = fmaf(whv[j], r, acc);
    }
    out[t] = fmaxf(acc, 0.0f);
}

extern "C" void kernel_launch(void* const* d_in, const int* in_sizes, int n_in,
                              void* d_out, int out_size, void* d_ws, size_t ws_size,
                              hipStream_t stream) {
    const float* x = (const float*)d_in[0];
    float* out = (float*)d_out;
    int total = out_size;  // 16*256*12*52 = 2,555,904
    int blocks = (total + 255) / 256;
    bicubic_relu_kernel<<<blocks, 256, 0, stream>>>(x, out, total);
}

// Round 2
// 29.365 us; speedup vs baseline: 1.0383x; 1.0383x over previous
//
#include <hip/hip_runtime.h>

// Bicubic resize (align_corners=True, PyTorch a=-0.75) from (N=4096, 224, 224)
// to (12, 52), fused with ReLU.
//
// R1 changes vs R0:
//  - The 4 W-taps are contiguous columns [w0-1, w0+2] for all interior ow ->
//    one 16B (dword-aligned) load per row-tap instead of 4 scalar gathers.
//    16 scattered loads/thread -> 4 vector loads/thread.
//  - Edge outputs (oh in {0,11}, ow in {0,51}) have t==0 exactly -> weights
//    collapse to a single tap. Instead of clamped indices (which fetched
//    zero-weight rows), point all 4 taps at the single needed row/col with
//    weights (1,0,0,0): duplicate loads are L1 hits, fetch drops 45->42
//    rows/plane, and the load path stays divergence-free.

#define A_COEF (-0.75f)
#define IN_H 224
#define IN_W 224
#define OUT_H 12
#define OUT_W 52

// 16-byte load with only 4-byte alignment guarantee (W window starts at an
// arbitrary column). gfx9+ supports unaligned global dwordx4.
struct __attribute__((packed, aligned(4))) f4u { float a, b, c, d; };

__device__ __forceinline__ float w_near(float s) {
    // |s| <= 1: (a+2)|s|^3 - (a+3)|s|^2 + 1
    return ((A_COEF + 2.0f) * s - (A_COEF + 3.0f)) * s * s + 1.0f;
}
__device__ __forceinline__ float w_far(float s) {
    // 1 < |s| < 2: a|s|^3 - 5a|s|^2 + 8a|s| - 4a
    return A_COEF * (((s - 5.0f) * s + 8.0f) * s - 4.0f);
}

__global__ __launch_bounds__(256) void bicubic_relu_kernel(
        const float* __restrict__ x, float* __restrict__ out, int total) {
    int t = blockIdx.x * 256 + threadIdx.x;
    if (t >= total) return;

    int ow    = t % OUT_W;
    int rest  = t / OUT_W;
    int oh    = rest % OUT_H;
    int plane = rest / OUT_H;

    // ---- W taps: contiguous window [wbase, wbase+3] + 4 weights ----
    int wbase;
    float ww0, ww1, ww2, ww3;
    if (ow == 0) {                     // t==0 exactly: only col 0
        wbase = 0;
        ww0 = 1.0f; ww1 = 0.0f; ww2 = 0.0f; ww3 = 0.0f;
    } else if (ow == OUT_W - 1) {      // t==0 exactly: only col 223
        wbase = IN_W - 4;
        ww0 = 0.0f; ww1 = 0.0f; ww2 = 0.0f; ww3 = 1.0f;
    } else {                           // interior: window within [3, 220]
        float srcw = ((float)(ow * (IN_W - 1))) / (float)(OUT_W - 1);
        int   w0   = (int)floorf(srcw);
        float tw   = srcw - (float)w0;
        wbase = w0 - 1;
        ww0 = w_far(1.0f + tw);
        ww1 = w_near(tw);
        ww2 = w_near(1.0f - tw);
        ww3 = w_far(2.0f - tw);
    }

    // ---- H taps: 4 row indices + 4 weights ----
    int hrow0, hrow1, hrow2, hrow3;
    float wh0, wh1, wh2, wh3;
    if (oh == 0) {                     // only row 0; duplicates are L1 hits
        hrow0 = hrow1 = hrow2 = hrow3 = 0;
        wh0 = 1.0f; wh1 = 0.0f; wh2 = 0.0f; wh3 = 0.0f;
    } else if (oh == OUT_H - 1) {      // only row 223
        hrow0 = hrow1 = hrow2 = hrow3 = IN_H - 1;
        wh0 = 1.0f; wh1 = 0.0f; wh2 = 0.0f; wh3 = 0.0f;
    } else {                           // interior: rows within [19, 204]
        float srch = ((float)(oh * (IN_H - 1))) / (float)(OUT_H - 1);
        int   h0   = (int)floorf(srch);
        float th   = srch - (float)h0;
        hrow0 = h0 - 1; hrow1 = h0; hrow2 = h0 + 1; hrow3 = h0 + 2;
        wh0 = w_far(1.0f + th);
        wh1 = w_near(th);
        wh2 = w_near(1.0f - th);
        wh3 = w_far(2.0f - th);
    }

    const float* p = x + (size_t)plane * (size_t)(IN_H * IN_W) + wbase;

    int   hr[4] = { hrow0, hrow1, hrow2, hrow3 };
    float wh[4] = { wh0,   wh1,   wh2,   wh3   };
    float acc = 0.0f;
    #pragma unroll
    for (int j = 0; j < 4; ++j) {
        f4u q = *reinterpret_cast<const f4u*>(p + hr[j] * IN_W);
        float r = ww0 * q.a;
        r = fmaf(ww1, q.b, r);
        r = fmaf(ww2, q.c, r);
        r = fmaf(ww3, q.d, r);
        acc = fmaf(wh[j], r, acc);
    }
    out[t] = fmaxf(acc, 0.0f);
}

extern "C" void kernel_launch(void* const* d_in, const int* in_sizes, int n_in,
                              void* d_out, int out_size, void* d_ws, size_t ws_size,
                              hipStream_t stream) {
    const float* x = (const float*)d_in[0];
    float* out = (float*)d_out;
    int total = out_size;  // 16*256*12*52 = 2,555,904
    int blocks = (total + 255) / 256;
    bicubic_relu_kernel<<<blocks, 256, 0, stream>>>(x, out, total);
}

// Round 3
// 28.671 us; speedup vs baseline: 1.0634x; 1.0242x over previous
//
#include <hip/hip_runtime.h>

// Bicubic resize (align_corners=True, PyTorch a=-0.75) from (N=4096, 224, 224)
// to (12, 52), fused with ReLU.
//
// R2 changes vs R1:
//  - Wave-per-(plane, oh) mapping: lanes 0..51 = ow. Each tap's load
//    instruction now touches exactly ONE input row (~14 cache lines vs ~70
//    with the flat mapping) -> ~4.5x fewer L1/TA line transactions.
//  - oh is wave-uniform, so edge-oh waves (single-tap collapse) branch
//    uniformly and issue exactly one load.

#define A_COEF (-0.75f)
#define IN_H 224
#define IN_W 224
#define OUT_H 12
#define OUT_W 52

// 16-byte load with only 4-byte alignment guarantee (window start arbitrary).
struct __attribute__((packed, aligned(4))) f4u { float a, b, c, d; };

__device__ __forceinline__ float w_near(float s) {
    return ((A_COEF + 2.0f) * s - (A_COEF + 3.0f)) * s * s + 1.0f;
}
__device__ __forceinline__ float w_far(float s) {
    return A_COEF * (((s - 5.0f) * s + 8.0f) * s - 4.0f);
}

__global__ __launch_bounds__(256) void bicubic_relu_kernel(
        const float* __restrict__ x, float* __restrict__ out) {
    int lane = threadIdx.x & 63;
    int gw   = blockIdx.x * 4 + (threadIdx.x >> 6);  // global wave id, 0..49151
    int oh    = gw % OUT_H;
    int plane = gw / OUT_H;
    if (lane >= OUT_W) return;
    int ow = lane;

    // ---- W taps: contiguous window [wbase, wbase+3] + 4 weights ----
    int wbase;
    float ww0, ww1, ww2, ww3;
    if (ow == 0) {                     // t==0 exactly: only col 0
        wbase = 0;
        ww0 = 1.0f; ww1 = 0.0f; ww2 = 0.0f; ww3 = 0.0f;
    } else if (ow == OUT_W - 1) {      // t==0 exactly: only col 223
        wbase = IN_W - 4;
        ww0 = 0.0f; ww1 = 0.0f; ww2 = 0.0f; ww3 = 1.0f;
    } else {                           // interior: window within [3, 220]
        float srcw = ((float)(ow * (IN_W - 1))) / (float)(OUT_W - 1);
        int   w0   = (int)floorf(srcw);
        float tw   = srcw - (float)w0;
        wbase = w0 - 1;
        ww0 = w_far(1.0f + tw);
        ww1 = w_near(tw);
        ww2 = w_near(1.0f - tw);
        ww3 = w_far(2.0f - tw);
    }

    const float* p = x + (size_t)plane * (size_t)(IN_H * IN_W) + wbase;
    float acc;

    if (oh == 0 || oh == OUT_H - 1) {
        // Wave-uniform: single row with weight 1 -> one load.
        int row = (oh == 0) ? 0 : (IN_H - 1);
        f4u q = *reinterpret_cast<const f4u*>(p + row * IN_W);
        float r = ww0 * q.a;
        r = fmaf(ww1, q.b, r);
        r = fmaf(ww2, q.c, r);
        acc = fmaf(ww3, q.d, r);
    } else {
        float srch = ((float)(oh * (IN_H - 1))) / (float)(OUT_H - 1);
        int   h0   = (int)floorf(srch);
        float th   = srch - (float)h0;
        float wh[4] = { w_far(1.0f + th), w_near(th),
                        w_near(1.0f - th), w_far(2.0f - th) };
        acc = 0.0f;
        #pragma unroll
        for (int j = 0; j < 4; ++j) {
            f4u q = *reinterpret_cast<const f4u*>(p + (h0 - 1 + j) * IN_W);
            float r = ww0 * q.a;
            r = fmaf(ww1, q.b, r);
            r = fmaf(ww2, q.c, r);
            r = fmaf(ww3, q.d, r);
            acc = fmaf(wh[j], r, acc);
        }
    }

    out[((size_t)plane * OUT_H + oh) * OUT_W + ow] = fmaxf(acc, 0.0f);
}

extern "C" void kernel_launch(void* const* d_in, const int* in_sizes, int n_in,
                              void* d_out, int out_size, void* d_ws, size_t ws_size,
                              hipStream_t stream) {
    const float* x = (const float*)d_in[0];
    float* out = (float*)d_out;
    // 4096 planes * 12 oh = 49152 waves; 4 waves per 256-thread block.
    int blocks = (4096 * OUT_H) / 4;  // 12288
    bicubic_relu_kernel<<<blocks, 256, 0, stream>>>(x, out);
}